// Round 4
// baseline (41.663 us; speedup 1.0000x reference)
//
#include <hip/hip_runtime.h>

// PatchStd: out = sqrt( boxconv7(x^2) - boxconv7(x)^2 ), uniform 7x7 weight w.
// x: [16, 1, 1024, 1024] fp32, zero padding 3 on each side.
//
// Uniform weight => conv = w * windowed sum. Each thread owns 4 adjacent
// output columns and an 8-row vertical strip. Per input row: 3 aligned
// float4 loads -> sliding-window horizontal 7-sums (x and x^2) -> 7-deep
// register ring. Vertical window kept as RUNNING sums (vh += new - oldest,
// 4 ops/col instead of 12). Loads go through 3 rotating raw buffers issued
// 3 rows ahead (static indices via full unroll) for deep MLP — round 2
// showed occupancy is scheduler-limited (36% @ VGPR=60), so VGPRs spent on
// ILP are free. 128-thread blocks (4096 total, 16/CU) for finer balance.
// Nontemporal stores keep the streamed output from evicting L2 input lines.

#define IMG_W 1024
#define IMG_H 1024
#define SH    8             // output rows per block strip
#define TPB   128           // threads/block; 4 cols/thread -> 512 cols/block

typedef float v4f __attribute__((ext_vector_type(4)));  // native vec for NT store

__global__ __launch_bounds__(TPB) void patchstd_kernel(
    const float* __restrict__ img, const float* __restrict__ wptr,
    float* __restrict__ out)
{
    const int tx = threadIdx.x;
    const int gx = blockIdx.x * TPB + tx;         // 0..255 column-group id
    const int c0 = gx << 2;                       // first of 4 output cols
    const int y0 = blockIdx.y * SH;               // first output row of strip
    const float* base  = img + (size_t)blockIdx.z * (IMG_W * IMG_H);
    float*       obase = out + (size_t)blockIdx.z * (IMG_W * IMG_H);
    const float w = wptr[0];

    const bool interior = (gx > 0) && (gx < 255); // all 12 cols in-range

    float rh[7][4];     // ring: horizontal 7-sums of x
    float rq[7][4];     // ring: horizontal 7-sums of x^2
    float vh[4] = {0.f, 0.f, 0.f, 0.f};           // running vertical sums
    float vq[4] = {0.f, 0.f, 0.f, 0.f};
    float raw[3][12];   // rotating raw-row buffers (loads 3 rows ahead)

    // Load 12 raw pixels (cols c0-4 .. c0+7) of input row `row`; zeros outside.
    auto load_raw = [&](int row, float* v) {
        if (row >= 0 && row < IMG_H) {
            const float* rp = base + row * IMG_W;
            if (interior) {
                float4 a = *reinterpret_cast<const float4*>(rp + c0 - 4);
                float4 b = *reinterpret_cast<const float4*>(rp + c0);
                float4 c = *reinterpret_cast<const float4*>(rp + c0 + 4);
                v[0]=a.x; v[1]=a.y; v[2]=a.z;  v[3]=a.w;
                v[4]=b.x; v[5]=b.y; v[6]=b.z;  v[7]=b.w;
                v[8]=c.x; v[9]=c.y; v[10]=c.z; v[11]=c.w;
            } else {
                #pragma unroll
                for (int i = 0; i < 12; ++i) {
                    int col = c0 - 4 + i;
                    v[i] = (col >= 0 && col < IMG_W) ? rp[col] : 0.f;
                }
            }
        } else {
            #pragma unroll
            for (int i = 0; i < 12; ++i) v[i] = 0.f;
        }
    };

    // Horizontal 7-sums for the 4 output columns from 12 raw values.
    // window for output col (c0+k) = v[k+1 .. k+7]
    auto hsum = [&](const float* v, float* h, float* q) {
        float s = v[1]+v[2]+v[3]+v[4]+v[5]+v[6]+v[7];
        h[0] = s;
        s = s - v[1] + v[8];  h[1] = s;
        s = s - v[2] + v[9];  h[2] = s;
        h[3] = s - v[3] + v[10];
        float sq[11];
        #pragma unroll
        for (int i = 1; i <= 10; ++i) sq[i] = v[i] * v[i];
        float t = sq[1]+sq[2]+sq[3]+sq[4]+sq[5]+sq[6]+sq[7];
        q[0] = t;
        t = t - sq[1] + sq[8];  q[1] = t;
        t = t - sq[2] + sq[9];  q[2] = t;
        q[3] = t - sq[3] + sq[10];
    };

    // Fill the pipeline: rows y0-3, y0-2, y0-1 in flight.
    load_raw(y0 - 3, raw[0]);
    load_raw(y0 - 2, raw[1]);
    load_raw(y0 - 1, raw[2]);

    // Prologue: rows y0-3 .. y0+2 -> ring slots 0..5, accumulating vh/vq.
    // Consuming raw[j%3] frees it for the prefetch of row y0+j.
    #pragma unroll
    for (int j = 0; j < 6; ++j) {
        hsum(raw[j % 3], rh[j], rq[j]);
        load_raw(y0 + j, raw[j % 3]);
        #pragma unroll
        for (int k = 0; k < 4; ++k) { vh[k] += rh[j][k]; vq[k] += rq[j][k]; }
    }
    #pragma unroll
    for (int k = 0; k < 4; ++k) { rh[6][k] = 0.f; rq[6][k] = 0.f; }

    // Main loop (full unroll: ring slot, buffer index, guards all static).
    // Iteration rr consumes input row y0+3+rr (in raw[rr%3]) and emits
    // output row y0+rr. Prefetches row y0+rr+6 while rows remain.
    #pragma unroll
    for (int rr = 0; rr < SH; ++rr) {
        const int s = (6 + rr) % 7;
        #pragma unroll
        for (int k = 0; k < 4; ++k) { vh[k] -= rh[s][k]; vq[k] -= rq[s][k]; }

        hsum(raw[rr % 3], rh[s], rq[s]);
        if (rr <= SH - 4) load_raw(y0 + rr + 6, raw[rr % 3]);

        float o[4];
        #pragma unroll
        for (int k = 0; k < 4; ++k) {
            vh[k] += rh[s][k]; vq[k] += rq[s][k];
            float mean = w * vh[k];
            float var  = fmaf(w, vq[k], -(mean * mean));
            o[k] = sqrtf(fmaxf(var, 0.f));
        }
        v4f ov; ov.x = o[0]; ov.y = o[1]; ov.z = o[2]; ov.w = o[3];
        __builtin_nontemporal_store(
            ov, reinterpret_cast<v4f*>(obase + (size_t)(y0 + rr) * IMG_W + c0));
    }
}

extern "C" void kernel_launch(void* const* d_in, const int* in_sizes, int n_in,
                              void* d_out, int out_size, void* d_ws, size_t ws_size,
                              hipStream_t stream) {
    const float* img = (const float*)d_in[0];
    const float* wt  = (const float*)d_in[1];
    float* out = (float*)d_out;
    const int batch = in_sizes[0] / (IMG_W * IMG_H);   // 16
    dim3 grid(IMG_W / (TPB * 4), IMG_H / SH, batch);   // (2, 128, 16) = 4096
    patchstd_kernel<<<grid, dim3(TPB, 1, 1), 0, stream>>>(img, wt, out);
}